// Round 15
// baseline (215.246 us; speedup 1.0000x reference)
//
#include <hip/hip_runtime.h>

#define LATENT 64
#define SUB_SHIFT 7
#define SUB_ROWS 128
#define COLBITS 17
#define COL_MASK ((1 << COLBITS) - 1)
#define TILE 4096
#define NSUB_PAD 1024

__device__ __forceinline__ unsigned short f2bf(float f) {
    unsigned u = __float_as_uint(f);
    unsigned r = (u + 0x7FFFu + ((u >> 16) & 1u)) >> 16;   // round-nearest-even
    return (unsigned short)r;
}

// ---------------------------------------------------------------------------
// Stage 1: per-tile sub-bucket histogram -> part[tile*nsub + s]
// ---------------------------------------------------------------------------
__global__ void __launch_bounds__(512) hist_kernel(const int* __restrict__ rows,
                                                   int* __restrict__ part, int E, int nsub) {
    __shared__ int h[NSUB_PAD];
    int t = threadIdx.x;
    int tb = blockIdx.x * TILE;
    for (int i = t; i < NSUB_PAD; i += 512) h[i] = 0;
    __syncthreads();
    #pragma unroll
    for (int k = 0; k < TILE / 512; ++k) {
        int e = tb + k * 512 + t;
        if (e < E) atomicAdd(&h[rows[e] >> SUB_SHIFT], 1);
    }
    __syncthreads();
    for (int i = t; i < nsub; i += 512) part[blockIdx.x * nsub + i] = h[i];
}

// ---------------------------------------------------------------------------
// Stage 2: per-bucket exclusive scan of part over tiles (in place) + tot[s].
// One block (1024 thr) per bucket; requires ntiles <= 1024.
// ---------------------------------------------------------------------------
__global__ void __launch_bounds__(1024) scanparts_kernel(int* __restrict__ part,
                                                         int* __restrict__ tot,
                                                         int nsub, int ntiles) {
    __shared__ int sc[1024];
    int s = blockIdx.x;
    int t = threadIdx.x;
    int v = (t < ntiles) ? part[t * nsub + s] : 0;
    sc[t] = v;
    __syncthreads();
    for (int o = 1; o < 1024; o <<= 1) {
        int u = (t >= o) ? sc[t - o] : 0;
        __syncthreads();
        sc[t] += u;
        __syncthreads();
    }
    if (t < ntiles) part[t * nsub + s] = sc[t] - v;   // exclusive over tiles
    if (t == 1023) tot[s] = sc[1023];
}

// ---------------------------------------------------------------------------
// Stage 3 (1 block): exclusive scan of tot -> csr0, tstart, stot
// tstart[s] = csr0[s] + 8*s  (8-payload gap => bins never share a 64B line)
// ---------------------------------------------------------------------------
__global__ void subscan_kernel(const int* __restrict__ tot_in, int* __restrict__ csr0,
                               int* __restrict__ tstart, int* __restrict__ stot, int nsub) {
    __shared__ int tot[NSUB_PAD];
    __shared__ int sc[256];
    int t = threadIdx.x;
    for (int i = t; i < NSUB_PAD; i += 256) tot[i] = (i < nsub) ? tot_in[i] : 0;
    __syncthreads();
    int c0 = tot[4 * t], c1 = tot[4 * t + 1], c2 = tot[4 * t + 2], c3 = tot[4 * t + 3];
    int csum = c0 + c1 + c2 + c3;
    sc[t] = csum;
    __syncthreads();
    for (int o = 1; o < 256; o <<= 1) {
        int u = (t >= o) ? sc[t - o] : 0;
        __syncthreads();
        sc[t] += u;
        __syncthreads();
    }
    int pre = sc[t] - csum;
    int s0 = 4 * t;
    if (s0 < nsub)     { csr0[s0] = pre;     stot[s0] = c0;     tstart[s0] = pre + 8 * s0; }
    pre += c0;
    if (s0 + 1 < nsub) { csr0[s0 + 1] = pre; stot[s0 + 1] = c1; tstart[s0 + 1] = pre + 8 * (s0 + 1); }
    pre += c1;
    if (s0 + 2 < nsub) { csr0[s0 + 2] = pre; stot[s0 + 2] = c2; tstart[s0 + 2] = pre + 8 * (s0 + 2); }
    pre += c2;
    if (s0 + 3 < nsub) { csr0[s0 + 3] = pre; stot[s0 + 3] = c3; tstart[s0 + 3] = pre + 8 * (s0 + 3); }
}

// ---------------------------------------------------------------------------
// Stage 4: direct placement into bins. Run start = tstart[b] + part[tile][b]
// (deterministic, no global atomics). Runs are tile-private => lines are
// single-block-owned => no cross-XCD write amplification.
// ---------------------------------------------------------------------------
__global__ void __launch_bounds__(512) place_kernel(
        const int* __restrict__ rows, const int* __restrict__ cols,
        const float* __restrict__ vals, const int* __restrict__ part,
        const int* __restrict__ tstart, int2* __restrict__ tmp, int E, int nsub) {
    __shared__ int gbase[NSUB_PAD];
    __shared__ int cur[NSUB_PAD];
    int t = threadIdx.x;
    int tb = blockIdx.x * TILE;
    for (int i = t; i < nsub; i += 512)
        gbase[i] = part[blockIdx.x * nsub + i] + tstart[i];
    for (int i = t; i < NSUB_PAD; i += 512) cur[i] = 0;
    __syncthreads();
    #pragma unroll
    for (int k = 0; k < TILE / 512; ++k) {
        int e = tb + k * 512 + t;
        if (e < E) {
            int r = rows[e];
            int b = r >> SUB_SHIFT;
            int p = gbase[b] + atomicAdd(&cur[b], 1);
            tmp[p] = make_int2(cols[e] | ((r & (SUB_ROWS - 1)) << COLBITS),
                               __float_as_int(vals[e]));
        }
    }
}

// ---------------------------------------------------------------------------
// f32 -> bf16 table, vectorized 4 at a time
// ---------------------------------------------------------------------------
__global__ void conv_bf16_kernel(const float* __restrict__ in,
                                 unsigned short* __restrict__ outb, long long n4) {
    long long i = (long long)blockIdx.x * blockDim.x + threadIdx.x;
    long long stride = (long long)gridDim.x * blockDim.x;
    for (; i < n4; i += stride) {
        float4 f = reinterpret_cast<const float4*>(in)[i];
        ushort4 o;
        o.x = f2bf(f.x); o.y = f2bf(f.y); o.z = f2bf(f.z); o.w = f2bf(f.w);
        reinterpret_cast<ushort4*>(outb)[i] = o;
    }
}

// ---------------------------------------------------------------------------
// Stage 5: one block (512 threads) per sub-bucket -> offcnt, sorted spair.
// ---------------------------------------------------------------------------
__global__ void __launch_bounds__(512) subsort_kernel(
        const int2* __restrict__ tmp, const int* __restrict__ tstart,
        const int* __restrict__ stot, const int* __restrict__ csr0,
        int2* __restrict__ oc, int2* __restrict__ spair, int N) {
    __shared__ int lcnt[SUB_ROWS], lpos[SUB_ROWS], lcur[SUB_ROWS];
    int s = blockIdx.x;
    int t = threadIdx.x;
    int beg = tstart[s], n = stot[s], c0 = csr0[s];
    if (t < SUB_ROWS) lcnt[t] = 0;
    __syncthreads();
    for (int i = t; i < n; i += blockDim.x)
        atomicAdd(&lcnt[(tmp[beg + i].x >> COLBITS) & (SUB_ROWS - 1)], 1);
    __syncthreads();
    if (t < SUB_ROWS) lpos[t] = lcnt[t];
    __syncthreads();
    for (int o = 1; o < SUB_ROWS; o <<= 1) {
        int u = (t < SUB_ROWS && t >= o) ? lpos[t - o] : 0;
        __syncthreads();
        if (t < SUB_ROWS) lpos[t] += u;
        __syncthreads();
    }
    if (t < SUB_ROWS) {
        int excl = lpos[t] - lcnt[t];
        lcur[t] = excl;
        int row = (s << SUB_SHIFT) + t;
        if (row < N) oc[row] = make_int2(c0 + excl, lcnt[t]);
    }
    __syncthreads();
    for (int i = t; i < n; i += blockDim.x) {
        int2 w = tmp[beg + i];
        int rl = (w.x >> COLBITS) & (SUB_ROWS - 1);
        int p = atomicAdd(&lcur[rl], 1);
        spair[c0 + p] = make_int2(w.x & COL_MASK, w.y);
    }
}

// ---------------------------------------------------------------------------
// Gather hops: one wave per row; lane l -> features {8f..8f+7} (f=l&7) of
// edge-slot (l>>3). Per 8 edges: one int2 spair load + one 16B uint4 gather
// (1024B/instr = 8 full rows). Combine via shfl_xor(8,16,32). f32 accumulate.
// ---------------------------------------------------------------------------

#define FMA8(G, V)                                                              \
    acc0 += (V) * __uint_as_float((G).x << 16);                                 \
    acc1 += (V) * __uint_as_float((G).x & 0xFFFF0000u);                         \
    acc2 += (V) * __uint_as_float((G).y << 16);                                 \
    acc3 += (V) * __uint_as_float((G).y & 0xFFFF0000u);                         \
    acc4 += (V) * __uint_as_float((G).z << 16);                                 \
    acc5 += (V) * __uint_as_float((G).z & 0xFFFF0000u);                         \
    acc6 += (V) * __uint_as_float((G).w << 16);                                 \
    acc7 += (V) * __uint_as_float((G).w & 0xFFFF0000u);

#define GATHER_CORE(TBL)                                                        \
    int el = lane >> 3;                                                         \
    int f  = lane & 7;                                                          \
    const uint4* tb4 = (const uint4*)(TBL);                                     \
    const int2* sp = spair + el;      /* octet edge pointer */                  \
    float acc0 = 0.f, acc1 = 0.f, acc2 = 0.f, acc3 = 0.f;                       \
    float acc4 = 0.f, acc5 = 0.f, acc6 = 0.f, acc7 = 0.f;                       \
    for (; e + 32 <= end; e += 32) {                                            \
        int2 w0 = sp[e];      int2 w1 = sp[e + 8];                              \
        int2 w2 = sp[e + 16]; int2 w3 = sp[e + 24];                             \
        uint4 g0 = tb4[(unsigned)w0.x * 8u + (unsigned)f];                      \
        uint4 g1 = tb4[(unsigned)w1.x * 8u + (unsigned)f];                      \
        uint4 g2 = tb4[(unsigned)w2.x * 8u + (unsigned)f];                      \
        uint4 g3 = tb4[(unsigned)w3.x * 8u + (unsigned)f];                      \
        float v0 = __int_as_float(w0.y), v1 = __int_as_float(w1.y);             \
        float v2 = __int_as_float(w2.y), v3 = __int_as_float(w3.y);             \
        FMA8(g0, v0)                                                            \
        FMA8(g1, v1)                                                            \
        FMA8(g2, v2)                                                            \
        FMA8(g3, v3)                                                            \
    }                                                                           \
    for (; e + 8 <= end; e += 8) {                                              \
        int2 w_ = sp[e];                                                        \
        uint4 g_ = tb4[(unsigned)w_.x * 8u + (unsigned)f];                      \
        float v_ = __int_as_float(w_.y);                                        \
        FMA8(g_, v_)                                                            \
    }                                                                           \
    if (e < end) {                                                              \
        int ei = e + el;                                                        \
        int ci = ei < end ? ei : end - 1;                                       \
        int2 w_ = spair[ci];                                                    \
        uint4 g_ = tb4[(unsigned)w_.x * 8u + (unsigned)f];                      \
        float v_ = (ei < end) ? __int_as_float(w_.y) : 0.f;                     \
        FMA8(g_, v_)                                                            \
    }                                                                           \
    acc0 += __shfl_xor(acc0, 8); acc0 += __shfl_xor(acc0, 16); acc0 += __shfl_xor(acc0, 32); \
    acc1 += __shfl_xor(acc1, 8); acc1 += __shfl_xor(acc1, 16); acc1 += __shfl_xor(acc1, 32); \
    acc2 += __shfl_xor(acc2, 8); acc2 += __shfl_xor(acc2, 16); acc2 += __shfl_xor(acc2, 32); \
    acc3 += __shfl_xor(acc3, 8); acc3 += __shfl_xor(acc3, 16); acc3 += __shfl_xor(acc3, 32); \
    acc4 += __shfl_xor(acc4, 8); acc4 += __shfl_xor(acc4, 16); acc4 += __shfl_xor(acc4, 32); \
    acc5 += __shfl_xor(acc5, 8); acc5 += __shfl_xor(acc5, 16); acc5 += __shfl_xor(acc5, 32); \
    acc6 += __shfl_xor(acc6, 8); acc6 += __shfl_xor(acc6, 16); acc6 += __shfl_xor(acc6, 32); \
    acc7 += __shfl_xor(acc7, 8); acc7 += __shfl_xor(acc7, 16); acc7 += __shfl_xor(acc7, 32);

__global__ void __launch_bounds__(256) spmm_gather1_kernel(
        const int2* __restrict__ oc, const int2* __restrict__ spair,
        const unsigned short* __restrict__ xb, unsigned short* __restrict__ axb, int N) {
    int wid = blockIdx.x * (blockDim.x >> 6) + (threadIdx.x >> 6);
    int lane = threadIdx.x & 63;
    if (wid >= N) return;
    int2 o = oc[wid];
    int e = o.x, end = o.x + o.y;
    GATHER_CORE(xb)
    if (el == 0) {
        uint4 pk;
        pk.x = (unsigned)f2bf(acc0) | ((unsigned)f2bf(acc1) << 16);
        pk.y = (unsigned)f2bf(acc2) | ((unsigned)f2bf(acc3) << 16);
        pk.z = (unsigned)f2bf(acc4) | ((unsigned)f2bf(acc5) << 16);
        pk.w = (unsigned)f2bf(acc6) | ((unsigned)f2bf(acc7) << 16);
        ((uint4*)axb)[(size_t)wid * 8 + f] = pk;
    }
}

__global__ void __launch_bounds__(256) spmm_gather2_kernel(
        const int2* __restrict__ oc, const int2* __restrict__ spair,
        const unsigned short* __restrict__ axb, const float* __restrict__ alpha,
        const float* __restrict__ x, float* __restrict__ out, int N) {
    int wid = blockIdx.x * (blockDim.x >> 6) + (threadIdx.x >> 6);
    int lane = threadIdx.x & 63;
    if (wid >= N) return;
    int2 o = oc[wid];
    int e = o.x, end = o.x + o.y;
    GATHER_CORE(axb)
    if (el == 0) {
        float a = 1.0f / (1.0f + __expf(-alpha[wid]));
        float4 xv0 = ((const float4*)x)[(size_t)wid * 16 + 2 * f];
        float4 xv1 = ((const float4*)x)[(size_t)wid * 16 + 2 * f + 1];
        float4 ov0, ov1;
        ov0.x = a * acc0 - xv0.x;
        ov0.y = a * acc1 - xv0.y;
        ov0.z = a * acc2 - xv0.z;
        ov0.w = a * acc3 - xv0.w;
        ov1.x = a * acc4 - xv1.x;
        ov1.y = a * acc5 - xv1.y;
        ov1.z = a * acc6 - xv1.z;
        ov1.w = a * acc7 - xv1.w;
        ((float4*)out)[(size_t)wid * 16 + 2 * f] = ov0;
        ((float4*)out)[(size_t)wid * 16 + 2 * f + 1] = ov1;
    }
}

// ---------------------------------------------------------------------------
// Fallback: atomic scatter path (if workspace too small)
// ---------------------------------------------------------------------------
__global__ void spmm_atomic_kernel(const int* __restrict__ rows, const int* __restrict__ cols,
                                   const float* __restrict__ vals, const float* __restrict__ x,
                                   float* __restrict__ y, int E) {
    long long tid = (long long)blockIdx.x * blockDim.x + threadIdx.x;
    long long total = (long long)E * 16;
    long long stride = (long long)gridDim.x * blockDim.x;
    for (; tid < total; tid += stride) {
        int e = (int)(tid >> 4);
        int q = (int)(tid & 15);
        int r = rows[e];
        int c = cols[e];
        float v = vals[e];
        float4 xv = reinterpret_cast<const float4*>(x)[(size_t)c * 16 + q];
        float* yp = y + (size_t)r * LATENT + q * 4;
        atomicAdd(yp + 0, v * xv.x);
        atomicAdd(yp + 1, v * xv.y);
        atomicAdd(yp + 2, v * xv.z);
        atomicAdd(yp + 3, v * xv.w);
    }
}

__global__ void finalize_kernel(const float* __restrict__ alpha, const float* __restrict__ x,
                                float* __restrict__ out, int N) {
    long long tid = (long long)blockIdx.x * blockDim.x + threadIdx.x;
    long long total = (long long)N * 16;
    long long stride = (long long)gridDim.x * blockDim.x;
    for (; tid < total; tid += stride) {
        int i = (int)(tid >> 4);
        float a = 1.0f / (1.0f + __expf(-alpha[i]));
        float4 ov = reinterpret_cast<float4*>(out)[tid];
        float4 xv = reinterpret_cast<const float4*>(x)[tid];
        ov.x = a * ov.x - xv.x;
        ov.y = a * ov.y - xv.y;
        ov.z = a * ov.z - xv.z;
        ov.w = a * ov.w - xv.w;
        reinterpret_cast<float4*>(out)[tid] = ov;
    }
}

// ---------------------------------------------------------------------------

extern "C" void kernel_launch(void* const* d_in, const int* in_sizes, int n_in,
                              void* d_out, int out_size, void* d_ws, size_t ws_size,
                              hipStream_t stream) {
    // setup_inputs order: t, x, alpha_train, edge_rows, edge_cols, edge_vals
    const float* x     = (const float*)d_in[1];
    const float* alpha = (const float*)d_in[2];
    const int*   rows  = (const int*)d_in[3];
    const int*   cols  = (const int*)d_in[4];
    const float* vals  = (const float*)d_in[5];

    const int N = in_sizes[2];   // 100000
    const int E = in_sizes[3];   // 3200000
    float* out = (float*)d_out;

    const int block = 256;
    const int nsub   = (N + SUB_ROWS - 1) >> SUB_SHIFT;   // 782
    const int ntiles = (E + TILE - 1) / TILE;             // 782

    auto align256 = [](size_t v) { return (v + 255) & ~(size_t)255; };

    // Region A: tmp (bin-sorted edges, alive through subsort), then reused
    // for xbf (bf16 x) + axbf (bf16 ax1).
    size_t tmp_bytes  = ((size_t)E + 8 * (size_t)nsub) * sizeof(int2);
    size_t xbf_bytes  = (size_t)N * LATENT * sizeof(unsigned short);
    size_t o_axbf_inA = align256(xbf_bytes);
    size_t bf_bytes   = o_axbf_inA + xbf_bytes;
    size_t RA = tmp_bytes > bf_bytes ? tmp_bytes : bf_bytes;

    size_t o_tmp    = 0;
    size_t o_spair  = align256(o_tmp + RA);
    size_t o_oc     = align256(o_spair + (size_t)E * sizeof(int2));
    size_t o_csr0   = align256(o_oc + (size_t)N * sizeof(int2));
    size_t o_tstart = align256(o_csr0 + (size_t)nsub * sizeof(int));
    size_t o_stot   = align256(o_tstart + (size_t)nsub * sizeof(int));
    size_t o_tot    = align256(o_stot + (size_t)nsub * sizeof(int));
    size_t needed   = o_tot + (size_t)nsub * sizeof(int);
    size_t part_bytes = (size_t)ntiles * nsub * sizeof(int);

    if (ws_size >= needed && nsub <= NSUB_PAD && N <= (1 << COLBITS) &&
        ntiles <= 1024 && part_bytes <= (size_t)E * sizeof(int2)) {
        char* ws = (char*)d_ws;
        int2*           tmp    = (int2*)(ws + o_tmp);
        unsigned short* xbf    = (unsigned short*)(ws + o_tmp);          // after subsort
        unsigned short* axbf   = (unsigned short*)(ws + o_tmp + o_axbf_inA);
        int2*           spair  = (int2*)(ws + o_spair);
        int*            part   = (int*)(ws + o_spair);   // aliases spair (dead before spair)
        int2*           oc     = (int2*)(ws + o_oc);
        int*            csr0   = (int*)(ws + o_csr0);
        int*            tstart = (int*)(ws + o_tstart);
        int*            stot   = (int*)(ws + o_stot);
        int*            tot    = (int*)(ws + o_tot);

        // Per-tile histograms (doubles as the global bucket histogram source)
        hist_kernel<<<ntiles, 512, 0, stream>>>(rows, part, E, nsub);
        // Exclusive scan of part over tiles (in place) + per-bucket totals
        scanparts_kernel<<<nsub, 1024, 0, stream>>>(part, tot, nsub, ntiles);
        // Global CSR/bin offsets
        subscan_kernel<<<1, 256, 0, stream>>>(tot, csr0, tstart, stot, nsub);
        // Direct placement into bins (deterministic run starts, no atomics on global)
        place_kernel<<<ntiles, 512, 0, stream>>>(rows, cols, vals, part, tstart, tmp, E, nsub);
        // Per-bucket row sort -> CSR
        subsort_kernel<<<nsub, 512, 0, stream>>>(tmp, tstart, stot, csr0, oc, spair, N);

        // tmp dead -> build bf16 x table in its region
        long long n4 = (long long)N * (LATENT / 4);
        conv_bf16_kernel<<<2048, 256, 0, stream>>>(x, xbf, n4);

        // Two gather hops (wave per row), 8 features/lane x 8 edge-slots
        int rows_per_block = block / 64;
        int grid_rows = (N + rows_per_block - 1) / rows_per_block;
        spmm_gather1_kernel<<<grid_rows, block, 0, stream>>>(oc, spair, xbf, axbf, N);
        spmm_gather2_kernel<<<grid_rows, block, 0, stream>>>(oc, spair, axbf,
                                                             alpha, x, out, N);
        return;
    }

    // Fallback: atomic scatter path
    {
        float* ax1 = (float*)d_ws;
        const size_t feat_bytes = (size_t)N * LATENT * sizeof(float);
        hipMemsetAsync(ax1, 0, feat_bytes, stream);
        hipMemsetAsync(out, 0, feat_bytes, stream);
        long long work = (long long)E * 16;
        int grid_spmm = (int)((work + block - 1) / block);
        spmm_atomic_kernel<<<grid_spmm, block, 0, stream>>>(rows, cols, vals, x, ax1, E);
        spmm_atomic_kernel<<<grid_spmm, block, 0, stream>>>(rows, cols, vals, ax1, out, E);
        long long fwork = (long long)N * 16;
        int grid_fin = (int)((fwork + block - 1) / block);
        finalize_kernel<<<grid_fin, block, 0, stream>>>(alpha, x, out, N);
    }
}

// Round 16
// 196.437 us; speedup vs baseline: 1.0958x; 1.0958x over previous
//
#include <hip/hip_runtime.h>

#define LATENT 64
#define SUB_SHIFT 7
#define SUB_ROWS 128
#define COLBITS 17
#define COL_MASK ((1 << COLBITS) - 1)
#define TILE 8192
#define NSUB_PAD 1024

__device__ __forceinline__ unsigned short f2bf(float f) {
    unsigned u = __float_as_uint(f);
    unsigned r = (u + 0x7FFFu + ((u >> 16) & 1u)) >> 16;   // round-nearest-even
    return (unsigned short)r;
}

// ---------------------------------------------------------------------------
// Stage 1: per-tile sub-bucket histogram -> part[tile*nsub + s]
// ---------------------------------------------------------------------------
__global__ void __launch_bounds__(512) hist_kernel(const int* __restrict__ rows,
                                                   int* __restrict__ part, int E, int nsub) {
    __shared__ int h[NSUB_PAD];
    int t = threadIdx.x;
    int tb = blockIdx.x * TILE;
    for (int i = t; i < NSUB_PAD; i += 512) h[i] = 0;
    __syncthreads();
    #pragma unroll
    for (int k = 0; k < TILE / 512; ++k) {
        int e = tb + k * 512 + t;
        if (e < E) atomicAdd(&h[rows[e] >> SUB_SHIFT], 1);
    }
    __syncthreads();
    for (int i = t; i < nsub; i += 512) part[blockIdx.x * nsub + i] = h[i];
}

// ---------------------------------------------------------------------------
// Stage 2: per-bucket exclusive scan of part over tiles -> pfx, tot[s].
// One block (512 thr) per bucket; requires ntiles <= 512.
// ---------------------------------------------------------------------------
__global__ void __launch_bounds__(512) scanparts_kernel(const int* __restrict__ part,
                                                        int* __restrict__ pfx,
                                                        int* __restrict__ tot,
                                                        int nsub, int ntiles) {
    __shared__ int sc[512];
    int s = blockIdx.x;
    int t = threadIdx.x;
    int v = (t < ntiles) ? part[t * nsub + s] : 0;
    sc[t] = v;
    __syncthreads();
    for (int o = 1; o < 512; o <<= 1) {
        int u = (t >= o) ? sc[t - o] : 0;
        __syncthreads();
        sc[t] += u;
        __syncthreads();
    }
    if (t < ntiles) pfx[t * nsub + s] = sc[t] - v;   // exclusive over tiles
    if (t == 511) tot[s] = sc[511];
}

// ---------------------------------------------------------------------------
// Stage 3 (1 block): exclusive scan of tot -> csr0, tstart, stot
// tstart[s] = csr0[s] + 8*s  (8-payload gap => bins never share a 64B line)
// ---------------------------------------------------------------------------
__global__ void subscan_kernel(const int* __restrict__ tot_in, int* __restrict__ csr0,
                               int* __restrict__ tstart, int* __restrict__ stot, int nsub) {
    __shared__ int tot[NSUB_PAD];
    __shared__ int sc[256];
    int t = threadIdx.x;
    for (int i = t; i < NSUB_PAD; i += 256) tot[i] = (i < nsub) ? tot_in[i] : 0;
    __syncthreads();
    int c0 = tot[4 * t], c1 = tot[4 * t + 1], c2 = tot[4 * t + 2], c3 = tot[4 * t + 3];
    int csum = c0 + c1 + c2 + c3;
    sc[t] = csum;
    __syncthreads();
    for (int o = 1; o < 256; o <<= 1) {
        int u = (t >= o) ? sc[t - o] : 0;
        __syncthreads();
        sc[t] += u;
        __syncthreads();
    }
    int pre = sc[t] - csum;
    int s0 = 4 * t;
    if (s0 < nsub)     { csr0[s0] = pre;     stot[s0] = c0;     tstart[s0] = pre + 8 * s0; }
    pre += c0;
    if (s0 + 1 < nsub) { csr0[s0 + 1] = pre; stot[s0 + 1] = c1; tstart[s0 + 1] = pre + 8 * (s0 + 1); }
    pre += c1;
    if (s0 + 2 < nsub) { csr0[s0 + 2] = pre; stot[s0 + 2] = c2; tstart[s0 + 2] = pre + 8 * (s0 + 2); }
    pre += c2;
    if (s0 + 3 < nsub) { csr0[s0 + 3] = pre; stot[s0 + 3] = c3; tstart[s0 + 3] = pre + 8 * (s0 + 3); }
}

// ---------------------------------------------------------------------------
// Stage 4: LDS-staged placement. Counts come from part (no internal histogram
// pass); run bases are deterministic (tstart + pfx - base, no global atomics).
// Runs are copied out by consecutive threads -> coalesced, single-block lines.
// ---------------------------------------------------------------------------
__global__ void __launch_bounds__(512, 2) place_kernel(
        const int* __restrict__ rows, const int* __restrict__ cols,
        const float* __restrict__ vals, const int* __restrict__ part,
        const int* __restrict__ pfx, const int* __restrict__ tstart,
        int2* __restrict__ tmp, int E, int nsub) {
    __shared__ int base[NSUB_PAD];
    __shared__ int gbase[NSUB_PAD];
    __shared__ int cur[NSUB_PAD];
    __shared__ int2 stage[TILE];
    __shared__ int sc[512];
    int t = threadIdx.x;
    int tb = blockIdx.x * TILE;
    int tilecnt = E - tb; if (tilecnt > TILE) tilecnt = TILE;

    // exclusive scan of this tile's counts -> base[]
    const int* pc = part + (size_t)blockIdx.x * nsub;
    int c0 = (2 * t < nsub) ? pc[2 * t] : 0;
    int c1 = (2 * t + 1 < nsub) ? pc[2 * t + 1] : 0;
    int csum = c0 + c1;
    sc[t] = csum;
    __syncthreads();
    for (int o = 1; o < 512; o <<= 1) {
        int u = (t >= o) ? sc[t - o] : 0;
        __syncthreads();
        sc[t] += u;
        __syncthreads();
    }
    int ex = sc[t] - csum;
    base[2 * t] = ex;
    base[2 * t + 1] = ex + c0;
    __syncthreads();
    for (int i = t; i < NSUB_PAD; i += 512) cur[i] = 0;
    for (int i = t; i < nsub; i += 512)
        gbase[i] = tstart[i] + pfx[(size_t)blockIdx.x * nsub + i] - base[i];
    __syncthreads();
    // place payloads into stage, sorted by bucket
    #pragma unroll
    for (int k = 0; k < TILE / 512; ++k) {
        int e = tb + k * 512 + t;
        if (e < E) {
            int r = rows[e];
            int b = r >> SUB_SHIFT;
            int pos = base[b] + atomicAdd(&cur[b], 1);
            stage[pos] = make_int2(cols[e] | ((r & (SUB_ROWS - 1)) << COLBITS),
                                   __float_as_int(vals[e]));
        }
    }
    __syncthreads();
    // coalesced copy-out: consecutive p -> consecutive dst within each run
    for (int p = t; p < tilecnt; p += 512) {
        int lo = 0, hi = nsub;
        while (hi - lo > 1) { int mid = (lo + hi) >> 1; if (base[mid] <= p) lo = mid; else hi = mid; }
        tmp[gbase[lo] + p] = stage[p];
    }
}

// ---------------------------------------------------------------------------
// f32 -> bf16 table, vectorized 4 at a time
// ---------------------------------------------------------------------------
__global__ void conv_bf16_kernel(const float* __restrict__ in,
                                 unsigned short* __restrict__ outb, long long n4) {
    long long i = (long long)blockIdx.x * blockDim.x + threadIdx.x;
    long long stride = (long long)gridDim.x * blockDim.x;
    for (; i < n4; i += stride) {
        float4 f = reinterpret_cast<const float4*>(in)[i];
        ushort4 o;
        o.x = f2bf(f.x); o.y = f2bf(f.y); o.z = f2bf(f.z); o.w = f2bf(f.w);
        reinterpret_cast<ushort4*>(outb)[i] = o;
    }
}

// ---------------------------------------------------------------------------
// Stage 5: one block (512 threads) per sub-bucket -> offcnt, sorted spair.
// ---------------------------------------------------------------------------
__global__ void __launch_bounds__(512) subsort_kernel(
        const int2* __restrict__ tmp, const int* __restrict__ tstart,
        const int* __restrict__ stot, const int* __restrict__ csr0,
        int2* __restrict__ oc, int2* __restrict__ spair, int N) {
    __shared__ int lcnt[SUB_ROWS], lpos[SUB_ROWS], lcur[SUB_ROWS];
    int s = blockIdx.x;
    int t = threadIdx.x;
    int beg = tstart[s], n = stot[s], c0 = csr0[s];
    if (t < SUB_ROWS) lcnt[t] = 0;
    __syncthreads();
    for (int i = t; i < n; i += blockDim.x)
        atomicAdd(&lcnt[(tmp[beg + i].x >> COLBITS) & (SUB_ROWS - 1)], 1);
    __syncthreads();
    if (t < SUB_ROWS) lpos[t] = lcnt[t];
    __syncthreads();
    for (int o = 1; o < SUB_ROWS; o <<= 1) {
        int u = (t < SUB_ROWS && t >= o) ? lpos[t - o] : 0;
        __syncthreads();
        if (t < SUB_ROWS) lpos[t] += u;
        __syncthreads();
    }
    if (t < SUB_ROWS) {
        int excl = lpos[t] - lcnt[t];
        lcur[t] = excl;
        int row = (s << SUB_SHIFT) + t;
        if (row < N) oc[row] = make_int2(c0 + excl, lcnt[t]);
    }
    __syncthreads();
    for (int i = t; i < n; i += blockDim.x) {
        int2 w = tmp[beg + i];
        int rl = (w.x >> COLBITS) & (SUB_ROWS - 1);
        int p = atomicAdd(&lcur[rl], 1);
        spair[c0 + p] = make_int2(w.x & COL_MASK, w.y);
    }
}

// ---------------------------------------------------------------------------
// Gather hops: one wave per row; lane l -> features {8f..8f+7} (f=l&7) of
// edge-slot (l>>3). Per 8 edges: one int2 spair load + one 16B uint4 gather
// (1024B/instr = 8 full rows). Combine via shfl_xor(8,16,32). f32 accumulate.
// ---------------------------------------------------------------------------

#define FMA8(G, V)                                                              \
    acc0 += (V) * __uint_as_float((G).x << 16);                                 \
    acc1 += (V) * __uint_as_float((G).x & 0xFFFF0000u);                         \
    acc2 += (V) * __uint_as_float((G).y << 16);                                 \
    acc3 += (V) * __uint_as_float((G).y & 0xFFFF0000u);                         \
    acc4 += (V) * __uint_as_float((G).z << 16);                                 \
    acc5 += (V) * __uint_as_float((G).z & 0xFFFF0000u);                         \
    acc6 += (V) * __uint_as_float((G).w << 16);                                 \
    acc7 += (V) * __uint_as_float((G).w & 0xFFFF0000u);

#define GATHER_CORE(TBL)                                                        \
    int el = lane >> 3;                                                         \
    int f  = lane & 7;                                                          \
    const uint4* tb4 = (const uint4*)(TBL);                                     \
    const int2* sp = spair + el;      /* octet edge pointer */                  \
    float acc0 = 0.f, acc1 = 0.f, acc2 = 0.f, acc3 = 0.f;                       \
    float acc4 = 0.f, acc5 = 0.f, acc6 = 0.f, acc7 = 0.f;                       \
    for (; e + 32 <= end; e += 32) {                                            \
        int2 w0 = sp[e];      int2 w1 = sp[e + 8];                              \
        int2 w2 = sp[e + 16]; int2 w3 = sp[e + 24];                             \
        uint4 g0 = tb4[(unsigned)w0.x * 8u + (unsigned)f];                      \
        uint4 g1 = tb4[(unsigned)w1.x * 8u + (unsigned)f];                      \
        uint4 g2 = tb4[(unsigned)w2.x * 8u + (unsigned)f];                      \
        uint4 g3 = tb4[(unsigned)w3.x * 8u + (unsigned)f];                      \
        float v0 = __int_as_float(w0.y), v1 = __int_as_float(w1.y);             \
        float v2 = __int_as_float(w2.y), v3 = __int_as_float(w3.y);             \
        FMA8(g0, v0)                                                            \
        FMA8(g1, v1)                                                            \
        FMA8(g2, v2)                                                            \
        FMA8(g3, v3)                                                            \
    }                                                                           \
    for (; e + 8 <= end; e += 8) {                                              \
        int2 w_ = sp[e];                                                        \
        uint4 g_ = tb4[(unsigned)w_.x * 8u + (unsigned)f];                      \
        float v_ = __int_as_float(w_.y);                                        \
        FMA8(g_, v_)                                                            \
    }                                                                           \
    if (e < end) {                                                              \
        int ei = e + el;                                                        \
        int ci = ei < end ? ei : end - 1;                                       \
        int2 w_ = spair[ci];                                                    \
        uint4 g_ = tb4[(unsigned)w_.x * 8u + (unsigned)f];                      \
        float v_ = (ei < end) ? __int_as_float(w_.y) : 0.f;                     \
        FMA8(g_, v_)                                                            \
    }                                                                           \
    acc0 += __shfl_xor(acc0, 8); acc0 += __shfl_xor(acc0, 16); acc0 += __shfl_xor(acc0, 32); \
    acc1 += __shfl_xor(acc1, 8); acc1 += __shfl_xor(acc1, 16); acc1 += __shfl_xor(acc1, 32); \
    acc2 += __shfl_xor(acc2, 8); acc2 += __shfl_xor(acc2, 16); acc2 += __shfl_xor(acc2, 32); \
    acc3 += __shfl_xor(acc3, 8); acc3 += __shfl_xor(acc3, 16); acc3 += __shfl_xor(acc3, 32); \
    acc4 += __shfl_xor(acc4, 8); acc4 += __shfl_xor(acc4, 16); acc4 += __shfl_xor(acc4, 32); \
    acc5 += __shfl_xor(acc5, 8); acc5 += __shfl_xor(acc5, 16); acc5 += __shfl_xor(acc5, 32); \
    acc6 += __shfl_xor(acc6, 8); acc6 += __shfl_xor(acc6, 16); acc6 += __shfl_xor(acc6, 32); \
    acc7 += __shfl_xor(acc7, 8); acc7 += __shfl_xor(acc7, 16); acc7 += __shfl_xor(acc7, 32);

__global__ void __launch_bounds__(256) spmm_gather1_kernel(
        const int2* __restrict__ oc, const int2* __restrict__ spair,
        const unsigned short* __restrict__ xb, unsigned short* __restrict__ axb, int N) {
    int wid = blockIdx.x * (blockDim.x >> 6) + (threadIdx.x >> 6);
    int lane = threadIdx.x & 63;
    if (wid >= N) return;
    int2 o = oc[wid];
    int e = o.x, end = o.x + o.y;
    GATHER_CORE(xb)
    if (el == 0) {
        uint4 pk;
        pk.x = (unsigned)f2bf(acc0) | ((unsigned)f2bf(acc1) << 16);
        pk.y = (unsigned)f2bf(acc2) | ((unsigned)f2bf(acc3) << 16);
        pk.z = (unsigned)f2bf(acc4) | ((unsigned)f2bf(acc5) << 16);
        pk.w = (unsigned)f2bf(acc6) | ((unsigned)f2bf(acc7) << 16);
        ((uint4*)axb)[(size_t)wid * 8 + f] = pk;
    }
}

__global__ void __launch_bounds__(256) spmm_gather2_kernel(
        const int2* __restrict__ oc, const int2* __restrict__ spair,
        const unsigned short* __restrict__ axb, const float* __restrict__ alpha,
        const float* __restrict__ x, float* __restrict__ out, int N) {
    int wid = blockIdx.x * (blockDim.x >> 6) + (threadIdx.x >> 6);
    int lane = threadIdx.x & 63;
    if (wid >= N) return;
    int2 o = oc[wid];
    int e = o.x, end = o.x + o.y;
    GATHER_CORE(axb)
    if (el == 0) {
        float a = 1.0f / (1.0f + __expf(-alpha[wid]));
        float4 xv0 = ((const float4*)x)[(size_t)wid * 16 + 2 * f];
        float4 xv1 = ((const float4*)x)[(size_t)wid * 16 + 2 * f + 1];
        float4 ov0, ov1;
        ov0.x = a * acc0 - xv0.x;
        ov0.y = a * acc1 - xv0.y;
        ov0.z = a * acc2 - xv0.z;
        ov0.w = a * acc3 - xv0.w;
        ov1.x = a * acc4 - xv1.x;
        ov1.y = a * acc5 - xv1.y;
        ov1.z = a * acc6 - xv1.z;
        ov1.w = a * acc7 - xv1.w;
        ((float4*)out)[(size_t)wid * 16 + 2 * f] = ov0;
        ((float4*)out)[(size_t)wid * 16 + 2 * f + 1] = ov1;
    }
}

// ---------------------------------------------------------------------------
// Fallback: atomic scatter path (if workspace too small)
// ---------------------------------------------------------------------------
__global__ void spmm_atomic_kernel(const int* __restrict__ rows, const int* __restrict__ cols,
                                   const float* __restrict__ vals, const float* __restrict__ x,
                                   float* __restrict__ y, int E) {
    long long tid = (long long)blockIdx.x * blockDim.x + threadIdx.x;
    long long total = (long long)E * 16;
    long long stride = (long long)gridDim.x * blockDim.x;
    for (; tid < total; tid += stride) {
        int e = (int)(tid >> 4);
        int q = (int)(tid & 15);
        int r = rows[e];
        int c = cols[e];
        float v = vals[e];
        float4 xv = reinterpret_cast<const float4*>(x)[(size_t)c * 16 + q];
        float* yp = y + (size_t)r * LATENT + q * 4;
        atomicAdd(yp + 0, v * xv.x);
        atomicAdd(yp + 1, v * xv.y);
        atomicAdd(yp + 2, v * xv.z);
        atomicAdd(yp + 3, v * xv.w);
    }
}

__global__ void finalize_kernel(const float* __restrict__ alpha, const float* __restrict__ x,
                                float* __restrict__ out, int N) {
    long long tid = (long long)blockIdx.x * blockDim.x + threadIdx.x;
    long long total = (long long)N * 16;
    long long stride = (long long)gridDim.x * blockDim.x;
    for (; tid < total; tid += stride) {
        int i = (int)(tid >> 4);
        float a = 1.0f / (1.0f + __expf(-alpha[i]));
        float4 ov = reinterpret_cast<float4*>(out)[tid];
        float4 xv = reinterpret_cast<const float4*>(x)[tid];
        ov.x = a * ov.x - xv.x;
        ov.y = a * ov.y - xv.y;
        ov.z = a * ov.z - xv.z;
        ov.w = a * ov.w - xv.w;
        reinterpret_cast<float4*>(out)[tid] = ov;
    }
}

// ---------------------------------------------------------------------------

extern "C" void kernel_launch(void* const* d_in, const int* in_sizes, int n_in,
                              void* d_out, int out_size, void* d_ws, size_t ws_size,
                              hipStream_t stream) {
    // setup_inputs order: t, x, alpha_train, edge_rows, edge_cols, edge_vals
    const float* x     = (const float*)d_in[1];
    const float* alpha = (const float*)d_in[2];
    const int*   rows  = (const int*)d_in[3];
    const int*   cols  = (const int*)d_in[4];
    const float* vals  = (const float*)d_in[5];

    const int N = in_sizes[2];   // 100000
    const int E = in_sizes[3];   // 3200000
    float* out = (float*)d_out;

    const int block = 256;
    const int nsub   = (N + SUB_ROWS - 1) >> SUB_SHIFT;   // 782
    const int ntiles = (E + TILE - 1) / TILE;             // 391

    auto align256 = [](size_t v) { return (v + 255) & ~(size_t)255; };

    // Region A: tmp (bin-sorted edges, alive through subsort), then reused
    // for xbf (bf16 x) + axbf (bf16 ax1).
    size_t tmp_bytes  = ((size_t)E + 8 * (size_t)nsub) * sizeof(int2);
    size_t xbf_bytes  = (size_t)N * LATENT * sizeof(unsigned short);
    size_t o_axbf_inA = align256(xbf_bytes);
    size_t bf_bytes   = o_axbf_inA + xbf_bytes;
    size_t RA = tmp_bytes > bf_bytes ? tmp_bytes : bf_bytes;

    size_t o_tmp    = 0;
    size_t o_spair  = align256(o_tmp + RA);
    size_t o_oc     = align256(o_spair + (size_t)E * sizeof(int2));
    size_t o_csr0   = align256(o_oc + (size_t)N * sizeof(int2));
    size_t o_tstart = align256(o_csr0 + (size_t)nsub * sizeof(int));
    size_t o_stot   = align256(o_tstart + (size_t)nsub * sizeof(int));
    size_t o_tot    = align256(o_stot + (size_t)nsub * sizeof(int));
    size_t needed   = o_tot + (size_t)nsub * sizeof(int);
    size_t part_bytes = (size_t)ntiles * nsub * sizeof(int);

    if (ws_size >= needed && nsub <= NSUB_PAD && N <= (1 << COLBITS) &&
        ntiles <= 512 && 2 * part_bytes <= (size_t)E * sizeof(int2)) {
        char* ws = (char*)d_ws;
        int2*           tmp    = (int2*)(ws + o_tmp);
        unsigned short* xbf    = (unsigned short*)(ws + o_tmp);          // after subsort
        unsigned short* axbf   = (unsigned short*)(ws + o_tmp + o_axbf_inA);
        int2*           spair  = (int2*)(ws + o_spair);
        int*            part   = (int*)(ws + o_spair);                   // aliases spair
        int*            pfx    = (int*)(ws + o_spair + part_bytes);      // aliases spair
        int2*           oc     = (int2*)(ws + o_oc);
        int*            csr0   = (int*)(ws + o_csr0);
        int*            tstart = (int*)(ws + o_tstart);
        int*            stot   = (int*)(ws + o_stot);
        int*            tot    = (int*)(ws + o_tot);

        // Per-tile histograms -> part
        hist_kernel<<<ntiles, 512, 0, stream>>>(rows, part, E, nsub);
        // Exclusive scan of part over tiles -> pfx, per-bucket totals -> tot
        scanparts_kernel<<<nsub, 512, 0, stream>>>(part, pfx, tot, nsub, ntiles);
        // Global CSR/bin offsets
        subscan_kernel<<<1, 256, 0, stream>>>(tot, csr0, tstart, stot, nsub);
        // LDS-staged placement with deterministic run bases
        place_kernel<<<ntiles, 512, 0, stream>>>(rows, cols, vals, part, pfx, tstart,
                                                 tmp, E, nsub);
        // Per-bucket row sort -> CSR
        subsort_kernel<<<nsub, 512, 0, stream>>>(tmp, tstart, stot, csr0, oc, spair, N);

        // tmp dead -> build bf16 x table in its region
        long long n4 = (long long)N * (LATENT / 4);
        conv_bf16_kernel<<<2048, 256, 0, stream>>>(x, xbf, n4);

        // Two gather hops (wave per row), 8 features/lane x 8 edge-slots
        int rows_per_block = block / 64;
        int grid_rows = (N + rows_per_block - 1) / rows_per_block;
        spmm_gather1_kernel<<<grid_rows, block, 0, stream>>>(oc, spair, xbf, axbf, N);
        spmm_gather2_kernel<<<grid_rows, block, 0, stream>>>(oc, spair, axbf,
                                                             alpha, x, out, N);
        return;
    }

    // Fallback: atomic scatter path
    {
        float* ax1 = (float*)d_ws;
        const size_t feat_bytes = (size_t)N * LATENT * sizeof(float);
        hipMemsetAsync(ax1, 0, feat_bytes, stream);
        hipMemsetAsync(out, 0, feat_bytes, stream);
        long long work = (long long)E * 16;
        int grid_spmm = (int)((work + block - 1) / block);
        spmm_atomic_kernel<<<grid_spmm, block, 0, stream>>>(rows, cols, vals, x, ax1, E);
        spmm_atomic_kernel<<<grid_spmm, block, 0, stream>>>(rows, cols, vals, ax1, out, E);
        long long fwork = (long long)N * 16;
        int grid_fin = (int)((fwork + block - 1) / block);
        finalize_kernel<<<grid_fin, block, 0, stream>>>(alpha, x, out, N);
    }
}